// Round 1
// baseline (850.718 us; speedup 1.0000x reference)
//
#include <hip/hip_runtime.h>

// LSTM: B=32768, T=512, I=2, H=16. One thread per (element, hidden unit):
// 16 lanes form an element group, 4 groups per wave, 4 waves per block.
// W_hh gate rows live in VGPRs (64 per thread); h[16] exchanged via LDS
// broadcast reads, fully intra-wave (no __syncthreads anywhere).

#define T_STEPS 512
#define HSZ 16

#if __has_builtin(__builtin_amdgcn_exp2f)
__device__ __forceinline__ float fexp2(float x) { return __builtin_amdgcn_exp2f(x); }
#else
__device__ __forceinline__ float fexp2(float x) { return exp2f(x); }
#endif

#if __has_builtin(__builtin_amdgcn_rcpf)
__device__ __forceinline__ float frcp(float x) { return __builtin_amdgcn_rcpf(x); }
#else
__device__ __forceinline__ float frcp(float x) { return 1.0f / x; }
#endif

// sigmoid(x) = 1/(1 + 2^(-x*log2(e))). Safe at extremes: exp2->inf => rcp->0; exp2->0 => 1.
__device__ __forceinline__ float fsigmoid(float x) {
    return frcp(1.0f + fexp2(x * -1.44269504088896340736f));
}
// tanh(x) = 1 - 2/(e^(2x)+1). Safe at extremes (exp2->inf => 1; exp2->0 => -1), no NaN.
__device__ __forceinline__ float ftanh(float x) {
    return 1.0f - 2.0f * frcp(1.0f + fexp2(x * 2.88539008177792681472f));
}

__global__ __launch_bounds__(256, 4)
void lstm_fused_kernel(const float* __restrict__ x,
                       const float* __restrict__ W_ih,
                       const float* __restrict__ W_hh,
                       const float* __restrict__ b_ih,
                       const float* __restrict__ b_hh,
                       const float* __restrict__ W1,
                       const float* __restrict__ b1,
                       const float* __restrict__ W2,
                       const float* __restrict__ b2,
                       float* __restrict__ out)
{
    __shared__ float h_sm[16][HSZ];   // [element-in-block][unit]; per-wave private rows

    const int tid  = threadIdx.x;
    const int wv   = tid >> 6;        // wave in block (0..3)
    const int lane = tid & 63;
    const int e    = lane >> 4;       // element group within wave (0..3)
    const int u    = lane & 15;       // hidden unit owned by this thread
    const int row  = wv * 4 + e;      // element within block (0..15)
    const int b    = blockIdx.x * 16 + row;

    // --- load this unit's 4 gate rows of W_hh (i,f,g,o = rows u, 16+u, 32+u, 48+u)
    float4 wrow[4][4];                // [gate][quarter of 16]
    #pragma unroll
    for (int g = 0; g < 4; ++g) {
        const float4* Wr = (const float4*)(W_hh + (size_t)(g * 16 + u) * HSZ);
        #pragma unroll
        for (int j = 0; j < 4; ++j) wrow[g][j] = Wr[j];
    }
    // W_ih rows (2 floats each) and combined biases
    float2 wih[4];
    float  bias[4];
    #pragma unroll
    for (int g = 0; g < 4; ++g) {
        const int r = g * 16 + u;
        wih[g]  = *(const float2*)(W_ih + 2 * r);
        bias[g] = b_ih[r] + b_hh[r];
    }

    const float2* xp = (const float2*)(x + (size_t)b * T_STEPS * 2);

    float h = 0.0f, c = 0.0f;

    for (int t = 0; t < T_STEPS; ++t) {
        // publish h for this element (intra-wave only -> no barrier)
        h_sm[row][u] = h;

        const float2 xv = xp[t];

        float acc[4];
        #pragma unroll
        for (int g = 0; g < 4; ++g)
            acc[g] = fmaf(wih[g].y, xv.y, fmaf(wih[g].x, xv.x, bias[g]));

        // gather full h-vector (broadcast reads; same wave wrote it above)
        float4 hh[4];
        #pragma unroll
        for (int j = 0; j < 4; ++j)
            hh[j] = *(const float4*)&h_sm[row][4 * j];

        #pragma unroll
        for (int j = 0; j < 4; ++j) {
            #pragma unroll
            for (int g = 0; g < 4; ++g) {
                acc[g] = fmaf(wrow[g][j].x, hh[j].x, acc[g]);
                acc[g] = fmaf(wrow[g][j].y, hh[j].y, acc[g]);
                acc[g] = fmaf(wrow[g][j].z, hh[j].z, acc[g]);
                acc[g] = fmaf(wrow[g][j].w, hh[j].w, acc[g]);
            }
        }

        const float si = fsigmoid(acc[0]);
        const float sf = fsigmoid(acc[1]);
        const float tg = ftanh(acc[2]);
        const float so = fsigmoid(acc[3]);

        c = fmaf(sf, c, si * tg);
        h = so * ftanh(c);
    }

    // ---- MLP head: y = tanh(h @ W1^T + b1) @ W2^T + b2
    h_sm[row][u] = h;                 // publish final h (intra-wave)

    float4 hh[4];
    #pragma unroll
    for (int j = 0; j < 4; ++j)
        hh[j] = *(const float4*)&h_sm[row][4 * j];

    const float4* W1r = (const float4*)(W1 + (size_t)u * HSZ);
    float z = b1[u];
    #pragma unroll
    for (int j = 0; j < 4; ++j) {
        const float4 wv4 = W1r[j];
        z = fmaf(wv4.x, hh[j].x, z);
        z = fmaf(wv4.y, hh[j].y, z);
        z = fmaf(wv4.z, hh[j].z, z);
        z = fmaf(wv4.w, hh[j].w, z);
    }
    z = ftanh(z);

    // reuse h_sm for z; all reads above are lockstep-before this write in the wave
    h_sm[row][u] = z;

    if (u < 2) {
        const float* W2r = W2 + (size_t)u * HSZ;
        float acc = b2[u];
        #pragma unroll
        for (int j = 0; j < HSZ; ++j)
            acc = fmaf(W2r[j], h_sm[row][j], acc);
        out[(size_t)b * 2 + u] = acc;
    }
}

extern "C" void kernel_launch(void* const* d_in, const int* in_sizes, int n_in,
                              void* d_out, int out_size, void* d_ws, size_t ws_size,
                              hipStream_t stream) {
    const float* x    = (const float*)d_in[0];
    const float* W_ih = (const float*)d_in[1];
    const float* W_hh = (const float*)d_in[2];
    const float* b_ih = (const float*)d_in[3];
    const float* b_hh = (const float*)d_in[4];
    const float* W1   = (const float*)d_in[5];
    const float* b1   = (const float*)d_in[6];
    const float* W2   = (const float*)d_in[7];
    const float* b2   = (const float*)d_in[8];
    float* out = (float*)d_out;

    const int n_blocks = 32768 / 16;   // 16 elements per 256-thread block
    lstm_fused_kernel<<<dim3(n_blocks), dim3(256), 0, stream>>>(
        x, W_ih, W_hh, b_ih, b_hh, W1, b1, W2, b2, out);
}

// Round 2
// 516.355 us; speedup vs baseline: 1.6475x; 1.6475x over previous
//
#include <hip/hip_runtime.h>

// LSTM B=32768, T=512, I=2, H=16 — MFMA recurrent matmul.
// Wave = 16 elements. A = W_hh (static, hi/lo split-bf16, 2 packs), B = h.
// Key invariant: MFMA C/D layout (lane 16q+e holds gate rows 4q+r of elem e)
// == B-operand layout for next step (lane 16q+e supplies k = units 4q+r of
// elem e, k-interleaved hi/lo). So the t-loop has NO LDS / cross-lane ops.

#define T_STEPS 512
#define LOG2E 1.44269504088896340736f

typedef __bf16 bf16x8 __attribute__((ext_vector_type(8)));
typedef float  f32x4  __attribute__((ext_vector_type(4)));
typedef unsigned int u32x4 __attribute__((ext_vector_type(4)));

union frag_u { u32x4 u; bf16x8 v; };

#if __has_builtin(__builtin_amdgcn_exp2f)
__device__ __forceinline__ float fexp2(float x) { return __builtin_amdgcn_exp2f(x); }
#else
__device__ __forceinline__ float fexp2(float x) { return exp2f(x); }
#endif
#if __has_builtin(__builtin_amdgcn_rcpf)
__device__ __forceinline__ float frcp(float x) { return __builtin_amdgcn_rcpf(x); }
#else
__device__ __forceinline__ float frcp(float x) { return 1.0f / x; }
#endif

__device__ __forceinline__ float fsigmoid(float x) {
    return frcp(1.0f + fexp2(x * -LOG2E));          // safe at +-inf
}
__device__ __forceinline__ float ftanh(float x) {
    return fmaf(-2.0f, frcp(1.0f + fexp2(x * (2.0f * LOG2E))), 1.0f);  // safe at +-inf
}

// split f32 -> (hi bf16 | lo bf16) by truncation; lo captures the residual.
// pack_hilo: low16 = hi-bf16, high16 = lo-bf16   (k=2u -> hi, k=2u+1 -> lo)
// pack_lohi: low16 = lo-bf16, high16 = hi-bf16   (swapped pack for cross terms)
__device__ __forceinline__ unsigned pack_hilo(float h) {
    unsigned hb = __float_as_uint(h);
    float    res = h - __uint_as_float(hb & 0xFFFF0000u);
#if __has_builtin(__builtin_amdgcn_perm)
    return __builtin_amdgcn_perm(__float_as_uint(res), hb, 0x07060302u);
#else
    return (hb >> 16) | (__float_as_uint(res) & 0xFFFF0000u);
#endif
}
__device__ __forceinline__ unsigned pack_lohi(float h) {
    unsigned hb = __float_as_uint(h);
    float    res = h - __uint_as_float(hb & 0xFFFF0000u);
#if __has_builtin(__builtin_amdgcn_perm)
    return __builtin_amdgcn_perm(__float_as_uint(res), hb, 0x03020706u);
#else
    return (__float_as_uint(res) >> 16) | (hb & 0xFFFF0000u);
#endif
}

__global__ __launch_bounds__(256, 2)
void lstm_mfma_kernel(const float* __restrict__ x,
                      const float* __restrict__ W_ih,
                      const float* __restrict__ W_hh,
                      const float* __restrict__ b_ih,
                      const float* __restrict__ b_hh,
                      const float* __restrict__ W1,
                      const float* __restrict__ b1,
                      const float* __restrict__ W2,
                      const float* __restrict__ b2,
                      float* __restrict__ out)
{
    __shared__ float hsm[4][16][16];   // head only; per-wave private, no barriers

    const int tid  = threadIdx.x;
    const int wv   = tid >> 6;
    const int lane = tid & 63;
    const int e    = lane & 15;        // elem within wave (C/D col, B col)
    const int q    = lane >> 4;        // quad (C/D row block, B k-block)

    // ---- static A fragments: W_hh gate tiles, split-bf16, 2 k-interleave packs.
    // A[m][k]: m = lane&15 -> gate row 16t + (lane&15); k = q*8+j -> unit 4q+(j>>1), part j&1.
    frag_u A1[4], A2[4];
    #pragma unroll
    for (int t = 0; t < 4; ++t) {
        const int row = 16 * t + (lane & 15);
        const float4 w4 = *(const float4*)(W_hh + row * 16 + 4 * q);
        const float wa[4] = {w4.x, w4.y, w4.z, w4.w};
        #pragma unroll
        for (int w = 0; w < 4; ++w) {
            A1[t].u[w] = pack_hilo(wa[w]);
            A2[t].u[w] = pack_lohi(wa[w]);
        }
    }

    // ---- x-proj weights + combined bias for the gate rows this lane's acc holds:
    // C/D: lane holds rows m = 4q + r (tile-local), i.e. global rows 16t + 4q + r.
    float wxw[4][4], wyw[4][4], bsw[4][4];
    #pragma unroll
    for (int t = 0; t < 4; ++t)
        #pragma unroll
        for (int r = 0; r < 4; ++r) {
            const int row = 16 * t + 4 * q + r;
            wxw[t][r] = W_ih[row * 2 + 0];
            wyw[t][r] = W_ih[row * 2 + 1];
            bsw[t][r] = b_ih[row] + b_hh[row];
        }

    const int gelem = blockIdx.x * 64 + wv * 16 + e;
    const float4* xp = (const float4*)(x + (size_t)gelem * (T_STEPS * 2));

    frag_u B;                          // h_{t-1} as B operand (split-bf16, interleaved)
    B.u[0] = 0u; B.u[1] = 0u; B.u[2] = 0u; B.u[3] = 0u;
    float c[4] = {0.f, 0.f, 0.f, 0.f};
    float h[4] = {0.f, 0.f, 0.f, 0.f};

    float4 xv = xp[0];                 // x[t=0..1] for this elem

    for (int t2 = 0; t2 < T_STEPS / 2; ++t2) {
        const float4 xnext = xp[(t2 + 1 < T_STEPS / 2) ? (t2 + 1) : 0];

        #pragma unroll
        for (int half = 0; half < 2; ++half) {
            const float xa = half ? xv.z : xv.x;
            const float xb = half ? xv.w : xv.y;

            f32x4 acc[4];
            #pragma unroll
            for (int t = 0; t < 4; ++t) {
                f32x4 ini;
                #pragma unroll
                for (int r = 0; r < 4; ++r)
                    ini[r] = fmaf(wxw[t][r], xa, fmaf(wyw[t][r], xb, bsw[t][r]));
                acc[t] = __builtin_amdgcn_mfma_f32_16x16x32_bf16(A1[t].v, B.v, ini, 0, 0, 0);
                acc[t] = __builtin_amdgcn_mfma_f32_16x16x32_bf16(A2[t].v, B.v, acc[t], 0, 0, 0);
            }

            #pragma unroll
            for (int r = 0; r < 4; ++r) {
                const float ig = fsigmoid(acc[0][r]);
                const float fg = fsigmoid(acc[1][r]);
                const float gg = ftanh(acc[2][r]);
                const float og = fsigmoid(acc[3][r]);
                c[r] = fmaf(fg, c[r], ig * gg);
                const float hn = og * ftanh(c[r]);
                h[r] = hn;
                B.u[r] = pack_hilo(hn);   // == next step's B operand word r
            }
        }
        xv = xnext;
    }

    // ---- MLP head: z = tanh(W1 h + b1); y = W2 z + b2. Intra-wave LDS, no barrier.
    #pragma unroll
    for (int r = 0; r < 4; ++r) hsm[wv][e][4 * q + r] = h[r];

    float hv[16];
    #pragma unroll
    for (int j = 0; j < 4; ++j) {
        const float4 t4 = *(const float4*)&hsm[wv][e][4 * j];
        hv[4 * j + 0] = t4.x; hv[4 * j + 1] = t4.y;
        hv[4 * j + 2] = t4.z; hv[4 * j + 3] = t4.w;
    }

    float z[4];
    #pragma unroll
    for (int r = 0; r < 4; ++r) {
        const int m = 4 * q + r;
        float a = b1[m];
        #pragma unroll
        for (int j = 0; j < 16; ++j) a = fmaf(W1[m * 16 + j], hv[j], a);
        z[r] = ftanh(a);
    }
    #pragma unroll
    for (int r = 0; r < 4; ++r) hsm[wv][e][4 * q + r] = z[r];

    if (q < 2) {
        float a = b2[q];
        #pragma unroll
        for (int j = 0; j < 16; ++j) a = fmaf(W2[q * 16 + j], hsm[wv][e][j], a);
        out[(size_t)gelem * 2 + q] = a;
    }
}

extern "C" void kernel_launch(void* const* d_in, const int* in_sizes, int n_in,
                              void* d_out, int out_size, void* d_ws, size_t ws_size,
                              hipStream_t stream) {
    const float* x    = (const float*)d_in[0];
    const float* W_ih = (const float*)d_in[1];
    const float* W_hh = (const float*)d_in[2];
    const float* b_ih = (const float*)d_in[3];
    const float* b_hh = (const float*)d_in[4];
    const float* W1   = (const float*)d_in[5];
    const float* b1   = (const float*)d_in[6];
    const float* W2   = (const float*)d_in[7];
    const float* b2   = (const float*)d_in[8];
    float* out = (float*)d_out;

    // 32768 elems / 64 per block (4 waves x 16) = 512 blocks
    lstm_mfma_kernel<<<dim3(512), dim3(256), 0, stream>>>(
        x, W_ih, W_hh, b_ih, b_hh, W1, b1, W2, b2, out);
}